// Round 6
// baseline (246.099 us; speedup 1.0000x reference)
//
#include <hip/hip_runtime.h>
#include <hip/hip_bf16.h>

// Problem constants: B=4, R=16384, S=96
#define NRAYS 65536
#define NS    96
#define NI    95

// Output layout (FP32, outputs concatenated flat in return order):
//   composite_rgb   : [0,        196608)
//   composite_depth : [196608,   262144)
//   weights         : [262144,   6488064)
//   composite_point : [6488064,  6684672)
//   tau             : [6684672,  6750208)
#define OFF_RGB   0
#define OFF_DEPTH 196608
#define OFF_W     262144
#define OFF_PT    6488064
#define OFF_TAU   6684672

__global__ void init_minmax(unsigned* ws) {
    ws[0] = 0x7f800000u;  // +inf (min slot)
    ws[1] = 0u;           // 0.0f (max slot; depths uniform[0,1) >= 0)
}

// depths sorted along S: global min = min over rays of d[ray][0],
//                        global max = max over rays of d[ray][95].
__global__ void depth_minmax(const float* __restrict__ deps, unsigned* ws) {
    int g = blockIdx.x * blockDim.x + threadIdx.x;
    float lo = deps[(size_t)g * NS];
    float hi = deps[(size_t)g * NS + NS - 1];
    #pragma unroll
    for (int off = 32; off; off >>= 1) {
        lo = fminf(lo, __shfl_xor(lo, off, 64));
        hi = fmaxf(hi, __shfl_xor(hi, off, 64));
    }
    if ((threadIdx.x & 63) == 0) {
        atomicMin(&ws[0], __float_as_uint(lo));
        atomicMax(&ws[1], __float_as_uint(hi));
    }
}

__device__ __forceinline__ float softplus_f(float x) {
    // jax.nn.softplus = log1p(exp(x)), numerically stable form
    return fmaxf(x, 0.0f) + log1pf(__expf(-fabsf(x)));
}

// Block = 256 threads = 4 waves = 4 rays. All ray data staged to LDS with
// coalesced float4 loads; lanes index LDS directly. Lane l owns intervals
// i0=2l, i1=2l+1 (valid if < 95). Value-path identical to rounds 2/4
// (bit-verified equivalent); only the OUTPUT dtype changed to fp32.
__launch_bounds__(256)
__global__ void raymarch(const float* __restrict__ colors,
                         const float* __restrict__ dens,
                         const float* __restrict__ deps,
                         const float* __restrict__ coords,
                         const int* __restrict__ wbp,
                         const unsigned* __restrict__ mm,
                         float* __restrict__ out) {
    __shared__ float4 sC4[288];      // 4 rays x 288 floats (colors)
    __shared__ float4 sP4[288];      // coords
    __shared__ float4 sD4[96];       // 4 rays x 96 floats (densities)
    __shared__ float4 sZ4[96];       // depths
    __shared__ float  sF[4 * NS];    // per-ray interval factors

    const int tid  = threadIdx.x;
    const int w    = tid >> 6;
    const int lane = tid & 63;
    const int g    = blockIdx.x * 4 + w;

    // ---- stage 4 rays into LDS (fully coalesced float4) ----
    {
        const float4* C4 = (const float4*)(colors + (size_t)blockIdx.x * (4 * NS * 3));
        const float4* P4 = (const float4*)(coords + (size_t)blockIdx.x * (4 * NS * 3));
        const float4* D4 = (const float4*)(dens   + (size_t)blockIdx.x * (4 * NS));
        const float4* Z4 = (const float4*)(deps   + (size_t)blockIdx.x * (4 * NS));
        for (int i = tid; i < 288; i += 256) { sC4[i] = C4[i]; sP4[i] = P4[i]; }
        if (tid < 96) { sD4[tid] = D4[tid]; sZ4[tid] = Z4[tid]; }
    }
    __syncthreads();

    const float* C = (const float*)sC4 + w * (NS * 3);
    const float* P = (const float*)sP4 + w * (NS * 3);
    const float* D = (const float*)sD4 + w * NS;
    const float* Z = (const float*)sZ4 + w * NS;
    float*       F = sF + w * NS;

    const int  i0 = 2 * lane, i1 = 2 * lane + 1;
    const bool v0 = (i0 < NI), v1 = (i1 < NI);

    // ---- interval i0: samples i0, i0+1 ----
    int s = v0 ? i0 : 0;
    float za = Z[s], zb = Z[s + 1];
    float sp = softplus_f(0.5f * (D[s] + D[s + 1]));
    float E  = __expf(-sp * (zb - za));
    float a0 = v0 ? (1.0f - E) : 0.0f;           // alpha
    float f0 = v0 ? (E + 1e-10f) : 1.0f;         // 1 - alpha + 1e-10
    float dm0  = 0.5f * (za + zb);
    float cm0x = 0.5f * (C[3*s] + C[3*s+3]);
    float cm0y = 0.5f * (C[3*s+1] + C[3*s+4]);
    float cm0z = 0.5f * (C[3*s+2] + C[3*s+5]);
    float pm0x = 0.5f * (P[3*s] + P[3*s+3]);
    float pm0y = 0.5f * (P[3*s+1] + P[3*s+4]);
    float pm0z = 0.5f * (P[3*s+2] + P[3*s+5]);

    // ---- interval i1: samples i1, i1+1 ----
    s = v1 ? i1 : 0;
    za = Z[s]; zb = Z[s + 1];
    sp = softplus_f(0.5f * (D[s] + D[s + 1]));
    E  = __expf(-sp * (zb - za));
    float a1 = v1 ? (1.0f - E) : 0.0f;
    float f1 = v1 ? (E + 1e-10f) : 1.0f;
    float dm1  = 0.5f * (za + zb);
    float cm1x = 0.5f * (C[3*s] + C[3*s+3]);
    float cm1y = 0.5f * (C[3*s+1] + C[3*s+4]);
    float cm1z = 0.5f * (C[3*s+2] + C[3*s+5]);
    float pm1x = 0.5f * (P[3*s] + P[3*s+3]);
    float pm1y = 0.5f * (P[3*s+1] + P[3*s+4]);
    float pm1z = 0.5f * (P[3*s+2] + P[3*s+5]);

    // ---- publish factors, then broadcast prefix-product (trans) ----
    if (v0) F[i0] = f0;
    if (v1) F[i1] = f1;
    __syncthreads();

    float p = 1.0f, t0 = 1.0f, t1 = 1.0f, tau = 1.0f;
    for (int j = 0; j < NI; ++j) {
        if (j == i0) t0 = p;          // trans[i] = prod_{k<i} f_k
        if (j == i1) t1 = p;
        if (j == NI - 1) tau = p;     // tau = trans[94]
        p *= F[j];                    // same-address LDS read: broadcast
    }

    float w0 = a0 * t0, w1 = a1 * t1;

    // ---- weights output (fp32) ----
    {
        size_t wb = (size_t)OFF_W + (size_t)g * NI;
        if (v0) out[wb + i0] = w0;
        if (v1) out[wb + i1] = w1;
    }

    // ---- composite sums (butterfly across the wave) ----
    float acc[8];
    acc[0] = w0 * cm0x + w1 * cm1x;
    acc[1] = w0 * cm0y + w1 * cm1y;
    acc[2] = w0 * cm0z + w1 * cm1z;
    acc[3] = w0 * pm0x + w1 * pm1x;
    acc[4] = w0 * pm0y + w1 * pm1y;
    acc[5] = w0 * pm0z + w1 * pm1z;
    acc[6] = w0 * dm0  + w1 * dm1;    // composite_depth
    acc[7] = w0 + w1;                 // weight_total
    #pragma unroll
    for (int k = 0; k < 8; ++k) {
        #pragma unroll
        for (int off = 32; off; off >>= 1)
            acc[k] += __shfl_xor(acc[k], off, 64);
    }

    if (lane == 0) {
        float add = (wbp != nullptr && wbp[0] != 0) ? (1.0f - acc[7]) : 0.0f;
        size_t rb = (size_t)OFF_RGB + (size_t)g * 3;
        out[rb + 0] = acc[0] + add;
        out[rb + 1] = acc[1] + add;
        out[rb + 2] = acc[2] + add;
        size_t pb = (size_t)OFF_PT + (size_t)g * 3;
        out[pb + 0] = acc[3];
        out[pb + 1] = acc[4];
        out[pb + 2] = acc[5];
        float cd = acc[6];
        if (cd != cd) cd = __int_as_float(0x7f800000);  // nan_to_num -> +inf
        float dmin = __uint_as_float(mm[0]);
        float dmax = __uint_as_float(mm[1]);
        cd = fminf(fmaxf(cd, dmin), dmax);              // jnp.clip(global min/max)
        out[OFF_DEPTH + g] = cd;
        out[OFF_TAU + g]   = tau;
    }
}

extern "C" void kernel_launch(void* const* d_in, const int* in_sizes, int n_in,
                              void* d_out, int out_size, void* d_ws, size_t ws_size,
                              hipStream_t stream) {
    // Bind inputs by element count (robust to slot permutation):
    //   4718592 -> colors then sample_coordinates (dict order within ties)
    //   1572864 -> densities then depths
    //   1       -> white_back
    const float* colors = nullptr; const float* coords = nullptr;
    const float* dens = nullptr;   const float* deps = nullptr;
    const int* wb = nullptr;
    int big = 0, small = 0;
    for (int i = 0; i < n_in; ++i) {
        if (in_sizes[i] == 4718592)      { if (big++ == 0) colors = (const float*)d_in[i]; else coords = (const float*)d_in[i]; }
        else if (in_sizes[i] == 1572864) { if (small++ == 0) dens = (const float*)d_in[i]; else deps = (const float*)d_in[i]; }
        else if (in_sizes[i] == 1)       { wb = (const int*)d_in[i]; }
    }
    if (!colors || !coords || !dens || !deps) {   // fallback: dict order
        colors = (const float*)d_in[0];
        dens   = (const float*)d_in[1];
        deps   = (const float*)d_in[2];
        coords = (const float*)d_in[3];
        wb     = (n_in > 4) ? (const int*)d_in[4] : nullptr;
    }
    float* out = (float*)d_out;
    unsigned* mm = (unsigned*)d_ws;

    init_minmax<<<1, 1, 0, stream>>>(mm);
    depth_minmax<<<NRAYS / 256, 256, 0, stream>>>(deps, mm);
    raymarch<<<NRAYS / 4, 256, 0, stream>>>(colors, dens, deps, coords, wb, mm, out);
}

// Round 7
// 244.661 us; speedup vs baseline: 1.0059x; 1.0059x over previous
//
#include <hip/hip_runtime.h>
#include <hip/hip_bf16.h>

// Problem constants: B=4, R=16384, S=96
#define NRAYS 65536
#define NS    96
#define NI    95

// Output layout (FP32, outputs concatenated flat in return order):
//   composite_rgb   : [0,        196608)
//   composite_depth : [196608,   262144)
//   weights         : [262144,   6488064)
//   composite_point : [6488064,  6684672)
//   tau             : [6684672,  6750208)
#define OFF_RGB   0
#define OFF_DEPTH 196608
#define OFF_W     262144
#define OFF_PT    6488064
#define OFF_TAU   6684672

// ---------------------------------------------------------------------------
// Whole-array depths min/max (== jnp.min(depths), jnp.max(depths)).
// Coalesced float4 grid-stride; wave butterfly; one atomic pair per wave.
// ws[0] init 0xFFFFFFFF (uint max) by memset, ws[1] init 0.
// Positive floats compare correctly as uints.
// ---------------------------------------------------------------------------
__global__ void depth_minmax_full(const float* __restrict__ deps, unsigned* ws) {
    const int nt = gridDim.x * blockDim.x;
    int t = blockIdx.x * blockDim.x + threadIdx.x;
    float lo = __int_as_float(0x7f800000);
    float hi = 0.0f;
    const float4* Z4 = (const float4*)deps;
    const int n4 = NRAYS * NS / 4;          // 1,572,864
    for (int i = t; i < n4; i += nt) {
        float4 z = Z4[i];
        lo = fminf(lo, fminf(fminf(z.x, z.y), fminf(z.z, z.w)));
        hi = fmaxf(hi, fmaxf(fmaxf(z.x, z.y), fmaxf(z.z, z.w)));
    }
    #pragma unroll
    for (int off = 32; off; off >>= 1) {
        lo = fminf(lo, __shfl_xor(lo, off, 64));
        hi = fmaxf(hi, __shfl_xor(hi, off, 64));
    }
    if ((threadIdx.x & 63) == 0) {
        atomicMin(&ws[0], __float_as_uint(lo));
        atomicMax(&ws[1], __float_as_uint(hi));
    }
}

__device__ __forceinline__ float softplus_fast(float x) {
    // softplus = max(x,0) + log(1 + exp(-|x|)); __logf/__expf are single
    // v_log/v_exp instrs (~1e-6 rel err; threshold headroom ~6x).
    return fmaxf(x, 0.0f) + __logf(1.0f + __expf(-fabsf(x)));
}

// ---------------------------------------------------------------------------
// One WAVE per ray, fully register-resident (no LDS arrays).
// Lane l owns intervals i0=2l, i1=2l+1 (valid if < 95) and loads samples
// 2l, 2l+1 via coalesced float2; sample 2l+2 comes from lane l+1 via shuffle.
// Transmittance via 6-step shfl_up inclusive scan of per-lane factor pairs.
// Value path verified: rounds 1/2/4/5 produced bit-identical outputs.
// ---------------------------------------------------------------------------
__launch_bounds__(256)
__global__ void raymarch(const float* __restrict__ colors,
                         const float* __restrict__ dens,
                         const float* __restrict__ deps,
                         const float* __restrict__ coords,
                         const int* __restrict__ wbp,
                         const unsigned* __restrict__ mm,
                         float* __restrict__ out) {
    const int lane = threadIdx.x & 63;
    const int g = blockIdx.x * 4 + (threadIdx.x >> 6);

    const bool v0 = (lane <= 47);  // interval 2l   <= 94
    const bool v1 = (lane <= 46);  // interval 2l+1 <= 94

    float2 dp = make_float2(0.f, 0.f);   // depths  [2l], [2l+1]
    float2 dn = make_float2(0.f, 0.f);   // dens    [2l], [2l+1]
    float2 c01 = make_float2(0.f, 0.f), c23 = make_float2(0.f, 0.f),
           c45 = make_float2(0.f, 0.f); // colors samples 2l,2l+1 (6 floats)
    float2 p01 = make_float2(0.f, 0.f), p23 = make_float2(0.f, 0.f),
           p45 = make_float2(0.f, 0.f); // coords
    if (v0) {
        const float2* dpp = (const float2*)(deps + (size_t)g * NS);
        const float2* dnp = (const float2*)(dens + (size_t)g * NS);
        dp = dpp[lane];
        dn = dnp[lane];
        const float2* cp = (const float2*)(colors + (size_t)g * NS * 3);
        c01 = cp[3 * lane + 0]; c23 = cp[3 * lane + 1]; c45 = cp[3 * lane + 2];
        const float2* pp = (const float2*)(coords + (size_t)g * NS * 3);
        p01 = pp[3 * lane + 0]; p23 = pp[3 * lane + 1]; p45 = pp[3 * lane + 2];
    }
    // sample 2l   = (c01.x, c01.y, c23.x);  sample 2l+1 = (c23.y, c45.x, c45.y)
    // sample 2l+2 = lane l+1's sample-2l slots
    const int src = (lane < 63) ? lane + 1 : 63;
    float d2  = __shfl(dp.x, src, 64);
    float n2  = __shfl(dn.x, src, 64);
    float cx2 = __shfl(c01.x, src, 64);
    float cy2 = __shfl(c01.y, src, 64);
    float cz2 = __shfl(c23.x, src, 64);
    float px2 = __shfl(p01.x, src, 64);
    float py2 = __shfl(p01.y, src, 64);
    float pz2 = __shfl(p23.x, src, 64);

    // interval i0 (samples 2l, 2l+1)
    float E0 = __expf(-softplus_fast(0.5f * (dn.x + dn.y)) * (dp.y - dp.x));
    float a0 = v0 ? (1.0f - E0) : 0.0f;        // alpha
    float f0 = v0 ? (E0 + 1e-10f) : 1.0f;      // 1 - alpha + 1e-10
    // interval i1 (samples 2l+1, 2l+2)
    float E1 = __expf(-softplus_fast(0.5f * (dn.y + n2)) * (d2 - dp.y));
    float a1 = v1 ? (1.0f - E1) : 0.0f;
    float f1 = v1 ? (E1 + 1e-10f) : 1.0f;

    // inclusive scan of per-lane factor product -> transmittance
    float incl = f0 * f1;
    #pragma unroll
    for (int off = 1; off < 64; off <<= 1) {
        float t = __shfl_up(incl, off, 64);
        if (lane >= off) incl *= t;
    }
    float excl = __shfl_up(incl, 1, 64);
    if (lane == 0) excl = 1.0f;
    float w0 = a0 * excl;              // weights[2l]   = alpha * trans
    float w1 = a1 * (excl * f0);       // weights[2l+1]
    float tau = __shfl(excl, 47, 64);  // trans[94]

    // midpoints
    float dm0 = 0.5f * (dp.x + dp.y), dm1 = 0.5f * (dp.y + d2);
    float cm0x = 0.5f * (c01.x + c23.y), cm0y = 0.5f * (c01.y + c45.x), cm0z = 0.5f * (c23.x + c45.y);
    float cm1x = 0.5f * (c23.y + cx2),   cm1y = 0.5f * (c45.x + cy2),   cm1z = 0.5f * (c45.y + cz2);
    float pm0x = 0.5f * (p01.x + p23.y), pm0y = 0.5f * (p01.y + p45.x), pm0z = 0.5f * (p23.x + p45.y);
    float pm1x = 0.5f * (p23.y + px2),   pm1y = 0.5f * (p45.x + py2),   pm1z = 0.5f * (p45.y + pz2);

    // weights output (fp32)
    {
        size_t wb = (size_t)OFF_W + (size_t)g * NI + 2 * lane;
        if (v0) out[wb]     = w0;
        if (v1) out[wb + 1] = w1;
    }

    // composite partial sums, butterfly-reduced across the wave
    float acc[8];
    acc[0] = w0 * cm0x + w1 * cm1x;
    acc[1] = w0 * cm0y + w1 * cm1y;
    acc[2] = w0 * cm0z + w1 * cm1z;
    acc[3] = w0 * pm0x + w1 * pm1x;
    acc[4] = w0 * pm0y + w1 * pm1y;
    acc[5] = w0 * pm0z + w1 * pm1z;
    acc[6] = w0 * dm0  + w1 * dm1;    // composite_depth
    acc[7] = w0 + w1;                 // weight_total
    #pragma unroll
    for (int k = 0; k < 8; ++k) {
        #pragma unroll
        for (int off = 32; off; off >>= 1)
            acc[k] += __shfl_xor(acc[k], off, 64);
    }

    if (lane == 0) {
        float add = (wbp != nullptr && wbp[0] != 0) ? (1.0f - acc[7]) : 0.0f;
        size_t rb = (size_t)OFF_RGB + (size_t)g * 3;
        out[rb + 0] = acc[0] + add;
        out[rb + 1] = acc[1] + add;
        out[rb + 2] = acc[2] + add;
        size_t pb = (size_t)OFF_PT + (size_t)g * 3;
        out[pb + 0] = acc[3];
        out[pb + 1] = acc[4];
        out[pb + 2] = acc[5];
        float cd = acc[6];
        if (cd != cd) cd = __int_as_float(0x7f800000);  // nan_to_num -> +inf
        float dmin = __uint_as_float(mm[0]);
        float dmax = __uint_as_float(mm[1]);
        cd = fminf(fmaxf(cd, dmin), dmax);              // jnp.clip(global min/max)
        out[OFF_DEPTH + g] = cd;
        out[OFF_TAU + g]   = tau;
    }
}

extern "C" void kernel_launch(void* const* d_in, const int* in_sizes, int n_in,
                              void* d_out, int out_size, void* d_ws, size_t ws_size,
                              hipStream_t stream) {
    const float* colors = (const float*)d_in[0];
    const float* dens   = (const float*)d_in[1];
    const float* deps   = (const float*)d_in[2];
    const float* coords = (const float*)d_in[3];
    const int*   wb     = (n_in > 4) ? (const int*)d_in[4] : nullptr;
    float* out = (float*)d_out;
    unsigned* mm = (unsigned*)d_ws;

    // ws init: min slot = 0xFFFFFFFF (uint-max), max slot = 0
    hipMemsetAsync(mm, 0xFF, 4, stream);
    hipMemsetAsync(mm + 1, 0x00, 4, stream);
    depth_minmax_full<<<256, 256, 0, stream>>>(deps, mm);
    raymarch<<<NRAYS / 4, 256, 0, stream>>>(colors, dens, deps, coords, wb, mm, out);
}